// Round 1
// baseline (1348.245 us; speedup 1.0000x reference)
//
#include <hip/hip_runtime.h>
#include <math.h>

// Problem constants
constexpr int BATCH = 8;
constexpr int SEQ   = 2048;
constexpr int DIM   = 512;   // d == e == 512

// GEMM tiling: 128x128 block tile, K-tile 16, 256 threads, 8x8 per thread
constexpr int BM = 128, BN = 128, BK = 16;
constexpr int TM = 8,  TN = 8;

// C[m,n] = alpha * sum_k A[m,k] * B[n,k]   (both row-major, K innermost: "NT")
__global__ __launch_bounds__(256) void gemm_nt(
    const float* __restrict__ A, int lda, long strideA,
    const float* __restrict__ Bm, int ldb, long strideB,
    float* __restrict__ C, int ldc, long strideC,
    int M, int Nn, int K, float alpha)
{
    __shared__ float As[BK][BM + 4];
    __shared__ float Bs[BK][BN + 4];
    const int bz = blockIdx.z;
    A  += (long)bz * strideA;
    Bm += (long)bz * strideB;
    C  += (long)bz * strideC;
    const int bm = blockIdx.y * BM;
    const int bn = blockIdx.x * BN;
    const int t  = threadIdx.x;
    const int tx = t & 15;   // n direction (16)
    const int ty = t >> 4;   // m direction (16)
    // load mapping: each thread loads 8 floats of a 128x16 tile:
    // row lr = t/2 (two threads per row), col base lc = (t&1)*8
    const int lr = t >> 1;
    const int lc = (t & 1) * 8;

    float acc[TM][TN];
#pragma unroll
    for (int i = 0; i < TM; i++)
#pragma unroll
        for (int j = 0; j < TN; j++) acc[i][j] = 0.f;

    for (int k0 = 0; k0 < K; k0 += BK) {
        const float* ap = A  + (long)(bm + lr) * lda + k0 + lc;
        const float* bp = Bm + (long)(bn + lr) * ldb + k0 + lc;
        float4 a0 = *(const float4*)(ap);
        float4 a1 = *(const float4*)(ap + 4);
        float4 b0 = *(const float4*)(bp);
        float4 b1 = *(const float4*)(bp + 4);
        __syncthreads();   // protect previous iteration's LDS reads
        As[lc + 0][lr] = a0.x; As[lc + 1][lr] = a0.y;
        As[lc + 2][lr] = a0.z; As[lc + 3][lr] = a0.w;
        As[lc + 4][lr] = a1.x; As[lc + 5][lr] = a1.y;
        As[lc + 6][lr] = a1.z; As[lc + 7][lr] = a1.w;
        Bs[lc + 0][lr] = b0.x; Bs[lc + 1][lr] = b0.y;
        Bs[lc + 2][lr] = b0.z; Bs[lc + 3][lr] = b0.w;
        Bs[lc + 4][lr] = b1.x; Bs[lc + 5][lr] = b1.y;
        Bs[lc + 6][lr] = b1.z; Bs[lc + 7][lr] = b1.w;
        __syncthreads();
#pragma unroll
        for (int kk = 0; kk < BK; kk++) {
            const float4 av0 = *(const float4*)&As[kk][ty * TM];
            const float4 av1 = *(const float4*)&As[kk][ty * TM + 4];
            const float4 bv0 = *(const float4*)&Bs[kk][tx * TN];
            const float4 bv1 = *(const float4*)&Bs[kk][tx * TN + 4];
            const float ar[8] = {av0.x, av0.y, av0.z, av0.w, av1.x, av1.y, av1.z, av1.w};
            const float br[8] = {bv0.x, bv0.y, bv0.z, bv0.w, bv1.x, bv1.y, bv1.z, bv1.w};
#pragma unroll
            for (int i = 0; i < TM; i++)
#pragma unroll
                for (int j = 0; j < TN; j++)
                    acc[i][j] = fmaf(ar[i], br[j], acc[i][j]);
        }
    }
#pragma unroll
    for (int i = 0; i < TM; i++) {
        float* cp = C + (long)(bm + ty * TM + i) * ldc + bn + tx * TN;
        float4 o0 = make_float4(alpha * acc[i][0], alpha * acc[i][1],
                                alpha * acc[i][2], alpha * acc[i][3]);
        float4 o1 = make_float4(alpha * acc[i][4], alpha * acc[i][5],
                                alpha * acc[i][6], alpha * acc[i][7]);
        *(float4*)(cp)     = o0;
        *(float4*)(cp + 4) = o1;
    }
}

// C[m,n] = alpha * sum_k A[m,k] * B[k,n]   ("NN": B row-major [K,N])
__global__ __launch_bounds__(256) void gemm_nn(
    const float* __restrict__ A, int lda, long strideA,
    const float* __restrict__ Bm, int ldb, long strideB,
    float* __restrict__ C, int ldc, long strideC,
    int M, int Nn, int K, float alpha)
{
    __shared__ float As[BK][BM + 4];
    __shared__ float Bs[BK][BN + 4];
    const int bz = blockIdx.z;
    A  += (long)bz * strideA;
    Bm += (long)bz * strideB;
    C  += (long)bz * strideC;
    const int bm = blockIdx.y * BM;
    const int bn = blockIdx.x * BN;
    const int t  = threadIdx.x;
    const int tx = t & 15;
    const int ty = t >> 4;
    const int lr = t >> 1;
    const int lc = (t & 1) * 8;
    // B tile (BK x BN) load mapping: linear idx i = 4*t and 4*t+1024
    const int bk0 = (4 * t) >> 7;          // k of first float4
    const int bn0 = (4 * t) & 127;         // n of first float4
    // second float4 is at k += 8 (1024/128), same n

    float acc[TM][TN];
#pragma unroll
    for (int i = 0; i < TM; i++)
#pragma unroll
        for (int j = 0; j < TN; j++) acc[i][j] = 0.f;

    for (int k0 = 0; k0 < K; k0 += BK) {
        const float* ap = A + (long)(bm + lr) * lda + k0 + lc;
        float4 a0 = *(const float4*)(ap);
        float4 a1 = *(const float4*)(ap + 4);
        const float* bp0 = Bm + (long)(k0 + bk0) * ldb + bn + bn0;
        const float* bp1 = Bm + (long)(k0 + bk0 + 8) * ldb + bn + bn0;
        float4 b0 = *(const float4*)(bp0);
        float4 b1 = *(const float4*)(bp1);
        __syncthreads();
        As[lc + 0][lr] = a0.x; As[lc + 1][lr] = a0.y;
        As[lc + 2][lr] = a0.z; As[lc + 3][lr] = a0.w;
        As[lc + 4][lr] = a1.x; As[lc + 5][lr] = a1.y;
        As[lc + 6][lr] = a1.z; As[lc + 7][lr] = a1.w;
        *(float4*)&Bs[bk0][bn0]     = b0;
        *(float4*)&Bs[bk0 + 8][bn0] = b1;
        __syncthreads();
#pragma unroll
        for (int kk = 0; kk < BK; kk++) {
            const float4 av0 = *(const float4*)&As[kk][ty * TM];
            const float4 av1 = *(const float4*)&As[kk][ty * TM + 4];
            const float4 bv0 = *(const float4*)&Bs[kk][tx * TN];
            const float4 bv1 = *(const float4*)&Bs[kk][tx * TN + 4];
            const float ar[8] = {av0.x, av0.y, av0.z, av0.w, av1.x, av1.y, av1.z, av1.w};
            const float br[8] = {bv0.x, bv0.y, bv0.z, bv0.w, bv1.x, bv1.y, bv1.z, bv1.w};
#pragma unroll
            for (int i = 0; i < TM; i++)
#pragma unroll
                for (int j = 0; j < TN; j++)
                    acc[i][j] = fmaf(ar[i], br[j], acc[i][j]);
        }
    }
#pragma unroll
    for (int i = 0; i < TM; i++) {
        float* cp = C + (long)(bm + ty * TM + i) * ldc + bn + tx * TN;
        float4 o0 = make_float4(alpha * acc[i][0], alpha * acc[i][1],
                                alpha * acc[i][2], alpha * acc[i][3]);
        float4 o1 = make_float4(alpha * acc[i][4], alpha * acc[i][5],
                                alpha * acc[i][6], alpha * acc[i][7]);
        *(float4*)(cp)     = o0;
        *(float4*)(cp + 4) = o1;
    }
}

// In-place row softmax over rows of length SEQ (=2048). One block per row.
__global__ __launch_bounds__(256) void softmax_rows(float* __restrict__ attn)
{
    const long row = blockIdx.x;
    float* p = attn + row * (long)SEQ;
    const int t = threadIdx.x;
    float4 v0 = *(const float4*)(p + t * 8);
    float4 v1 = *(const float4*)(p + t * 8 + 4);

    float m = fmaxf(fmaxf(fmaxf(v0.x, v0.y), fmaxf(v0.z, v0.w)),
                    fmaxf(fmaxf(v1.x, v1.y), fmaxf(v1.z, v1.w)));
#pragma unroll
    for (int off = 32; off > 0; off >>= 1) m = fmaxf(m, __shfl_xor(m, off));
    __shared__ float sm[4];
    __shared__ float ss[4];
    const int wave = t >> 6;
    if ((t & 63) == 0) sm[wave] = m;
    __syncthreads();
    m = fmaxf(fmaxf(sm[0], sm[1]), fmaxf(sm[2], sm[3]));

    v0.x = __expf(v0.x - m); v0.y = __expf(v0.y - m);
    v0.z = __expf(v0.z - m); v0.w = __expf(v0.w - m);
    v1.x = __expf(v1.x - m); v1.y = __expf(v1.y - m);
    v1.z = __expf(v1.z - m); v1.w = __expf(v1.w - m);

    float s = v0.x + v0.y + v0.z + v0.w + v1.x + v1.y + v1.z + v1.w;
#pragma unroll
    for (int off = 32; off > 0; off >>= 1) s += __shfl_xor(s, off);
    if ((t & 63) == 0) ss[wave] = s;
    __syncthreads();
    s = ss[0] + ss[1] + ss[2] + ss[3];
    const float inv = 1.0f / s;

    v0.x *= inv; v0.y *= inv; v0.z *= inv; v0.w *= inv;
    v1.x *= inv; v1.y *= inv; v1.z *= inv; v1.w *= inv;
    *(float4*)(p + t * 8)     = v0;
    *(float4*)(p + t * 8 + 4) = v1;
}

extern "C" void kernel_launch(void* const* d_in, const int* in_sizes, int n_in,
                              void* d_out, int out_size, void* d_ws, size_t ws_size,
                              hipStream_t stream)
{
    const float* q  = (const float*)d_in[0];
    const float* k  = (const float*)d_in[1];
    const float* v  = (const float*)d_in[2];
    const float* Wq = (const float*)d_in[3];
    const float* Wk = (const float*)d_in[4];
    const float* Wv = (const float*)d_in[5];

    float* out  = (float*)d_out;                                   // [8,2048,512]
    float* attn = (float*)d_out + (size_t)BATCH * SEQ * DIM;       // [8,2048,2048]

    float* qp = (float*)d_ws;                                      // [8*2048,512]
    float* kp = qp + (size_t)BATCH * SEQ * DIM;
    float* vp = kp + (size_t)BATCH * SEQ * DIM;

    const float c = 0.044194173824159216f;  // 1/sqrt(512) — both proj scale and dots scale

    dim3 blk(256);

    // Projections: M = 8*2048, N = 512, K = 512, B = W (NT since W is [e,d])
    dim3 gproj(DIM / BN, (BATCH * SEQ) / BM, 1);
    gemm_nt<<<gproj, blk, 0, stream>>>(q, DIM, 0, Wq, DIM, 0, qp, DIM, 0,
                                       BATCH * SEQ, DIM, DIM, c);
    gemm_nt<<<gproj, blk, 0, stream>>>(k, DIM, 0, Wk, DIM, 0, kp, DIM, 0,
                                       BATCH * SEQ, DIM, DIM, c);
    gemm_nt<<<gproj, blk, 0, stream>>>(v, DIM, 0, Wv, DIM, 0, vp, DIM, 0,
                                       BATCH * SEQ, DIM, DIM, c);

    // Logits: per batch, dots[n,m] = scale * sum_e qp[n,e] kp[m,e]  (NT), into attn slice
    dim3 gdots(SEQ / BN, SEQ / BM, BATCH);
    gemm_nt<<<gdots, blk, 0, stream>>>(qp, DIM, (long)SEQ * DIM,
                                       kp, DIM, (long)SEQ * DIM,
                                       attn, SEQ, (long)SEQ * SEQ,
                                       SEQ, SEQ, DIM, c);

    // Softmax in place over the last axis
    softmax_rows<<<dim3(BATCH * SEQ), blk, 0, stream>>>(attn);

    // out[n,e] = sum_m attn[n,m] vp[m,e]  (NN), per batch
    dim3 gout(DIM / BN, SEQ / BM, BATCH);
    gemm_nn<<<gout, blk, 0, stream>>>(attn, SEQ, (long)SEQ * SEQ,
                                      vp, DIM, (long)SEQ * DIM,
                                      out, DIM, (long)SEQ * DIM,
                                      SEQ, DIM, SEQ, 1.0f);
}

// Round 3
// 584.962 us; speedup vs baseline: 2.3048x; 2.3048x over previous
//
#include <hip/hip_runtime.h>
#include <math.h>

constexpr int BATCH = 8;
constexpr int SEQ   = 2048;
constexpr int DIM   = 512;

typedef _Float16 f16x8 __attribute__((ext_vector_type(8)));
typedef float    f32x16 __attribute__((ext_vector_type(16)));

// ---------------------------------------------------------------------------
// NT MFMA GEMM: C[m,n] = alpha * sum_k A[m,k] * B[n,k], A,B row-major fp32.
// 128x128 block tile, BK=32, 256 threads = 4 waves, each wave a 64x64 region
// as 2x2 tiles of v_mfma_f32_32x32x16_f16.
// NSPLIT=3: fp32-accurate via fp16 hi/lo split (AhBh + AhBl + AlBh, ~2^-22).
// NSPLIT=1: plain fp16 (used only on the V path; feeds only `out`).
// ---------------------------------------------------------------------------
template<int NSPLIT>
__global__ __launch_bounds__(256) void gemm_nt_mfma(
    const float* __restrict__ A, int lda, long sA,
    const float* __restrict__ B, int ldb, long sB,
    float* __restrict__ C, int ldc, long sC,
    int K, float alpha)
{
    constexpr bool SPLIT = (NSPLIT > 1);
    // LDS frag layout: [k-chunk 0..3][row 0..127][8 contiguous k halves]
    __shared__ _Float16 AsH[4][128][8];
    __shared__ _Float16 BsH[4][128][8];
    __shared__ _Float16 AsL[SPLIT ? 4 : 1][SPLIT ? 128 : 1][8];
    __shared__ _Float16 BsL[SPLIT ? 4 : 1][SPLIT ? 128 : 1][8];

    const int bz = blockIdx.z;
    A += (long)bz * sA;  B += (long)bz * sB;  C += (long)bz * sC;
    const long bm = (long)blockIdx.y * 128;
    const long bn = (long)blockIdx.x * 128;
    const int t    = threadIdx.x;
    const int lane = t & 63;
    const int wave = t >> 6;
    const int wm = (wave >> 1) * 64;   // wave m-origin within block
    const int wn = (wave & 1)  * 64;   // wave n-origin within block
    const int ml = lane & 31;          // row/col within a 32-tile
    const int kh = lane >> 5;          // k-half selector (0/1)

    // staging: thread covers row r, k-range kc..kc+15 (chunks c0, c0+1)
    const int r  = t >> 1;
    const int c0 = (t & 1) * 2;
    const int kc = (t & 1) * 16;

    f32x16 acc[2][2] = {};

    const float* ap = A + (bm + r) * (long)lda + kc;
    const float* bp = B + (bn + r) * (long)ldb + kc;

    for (int k0 = 0; k0 < K; k0 += 32) {
        float4 av[4], bv[4];
#pragma unroll
        for (int i = 0; i < 4; i++) av[i] = *(const float4*)(ap + 4 * i);
#pragma unroll
        for (int i = 0; i < 4; i++) bv[i] = *(const float4*)(bp + 4 * i);
        ap += 32; bp += 32;

        __syncthreads();   // previous iter's LDS reads complete
        {
            const float* af = (const float*)av;
            const float* bf = (const float*)bv;
#pragma unroll
            for (int cc = 0; cc < 2; cc++) {
                f16x8 ha, la, hb, lb;
#pragma unroll
                for (int i = 0; i < 8; i++) {
                    float x = af[cc * 8 + i];
                    _Float16 hi = (_Float16)x;
                    ha[i] = hi;
                    if constexpr (SPLIT) la[i] = (_Float16)(x - (float)hi);
                    float y = bf[cc * 8 + i];
                    _Float16 hj = (_Float16)y;
                    hb[i] = hj;
                    if constexpr (SPLIT) lb[i] = (_Float16)(y - (float)hj);
                }
                *(f16x8*)&AsH[c0 + cc][r][0] = ha;
                *(f16x8*)&BsH[c0 + cc][r][0] = hb;
                if constexpr (SPLIT) {
                    *(f16x8*)&AsL[c0 + cc][r][0] = la;
                    *(f16x8*)&BsL[c0 + cc][r][0] = lb;
                }
            }
        }
        __syncthreads();

#pragma unroll
        for (int s = 0; s < 2; s++) {
            const int ch = 2 * s + kh;
            f16x8 Ah[2], Bh[2], Al[2], Bl[2];
#pragma unroll
            for (int i = 0; i < 2; i++) {
                Ah[i] = *(const f16x8*)&AsH[ch][wm + i * 32 + ml][0];
                Bh[i] = *(const f16x8*)&BsH[ch][wn + i * 32 + ml][0];
                if constexpr (SPLIT) {
                    Al[i] = *(const f16x8*)&AsL[ch][wm + i * 32 + ml][0];
                    Bl[i] = *(const f16x8*)&BsL[ch][wn + i * 32 + ml][0];
                }
            }
#pragma unroll
            for (int i = 0; i < 2; i++)
#pragma unroll
                for (int j = 0; j < 2; j++) {
                    acc[i][j] = __builtin_amdgcn_mfma_f32_32x32x16_f16(Ah[i], Bh[j], acc[i][j], 0, 0, 0);
                    if constexpr (SPLIT) {
                        acc[i][j] = __builtin_amdgcn_mfma_f32_32x32x16_f16(Ah[i], Bl[j], acc[i][j], 0, 0, 0);
                        acc[i][j] = __builtin_amdgcn_mfma_f32_32x32x16_f16(Al[i], Bh[j], acc[i][j], 0, 0, 0);
                    }
                }
        }
    }

    // Epilogue. C/D layout: col = lane&31; row = (reg&3) + 8*(reg>>2) + 4*(lane>>5)
#pragma unroll
    for (int i = 0; i < 2; i++)
#pragma unroll
        for (int j = 0; j < 2; j++) {
            const long col = bn + wn + j * 32 + ml;
#pragma unroll
            for (int rg = 0; rg < 16; rg++) {
                const long row = bm + wm + i * 32 + (rg & 3) + 8 * (rg >> 2) + 4 * kh;
                C[row * (long)ldc + col] = alpha * acc[i][j][rg];
            }
        }
}

// ---------------------------------------------------------------------------
// Small fp32 TN GEMM: C[i,j] = alpha * sum_e A[e,i] * B[e,j].  (P = c^2 Wk^T Wq)
// 64x64 tiles, 256 threads, 4x4 microtile. Only 512x512x512 — accuracy anchor.
// ---------------------------------------------------------------------------
__global__ __launch_bounds__(256) void gemm_tn_f32(
    const float* __restrict__ A, int lda,
    const float* __restrict__ B, int ldb,
    float* __restrict__ C, int ldc, int K, float alpha)
{
    __shared__ float As[16][68];
    __shared__ float Bs[16][68];
    const int bm = blockIdx.y * 64;
    const int bn = blockIdx.x * 64;
    const int t  = threadIdx.x;
    const int tx = t & 15, ty = t >> 4;
    const int kk = t >> 4, mc = (t & 15) * 4;

    float acc[4][4] = {};
    for (int k0 = 0; k0 < K; k0 += 16) {
        float4 a = *(const float4*)(A + (long)(k0 + kk) * lda + bm + mc);
        float4 b = *(const float4*)(B + (long)(k0 + kk) * ldb + bn + mc);
        __syncthreads();
        As[kk][mc] = a.x; As[kk][mc + 1] = a.y; As[kk][mc + 2] = a.z; As[kk][mc + 3] = a.w;
        Bs[kk][mc] = b.x; Bs[kk][mc + 1] = b.y; Bs[kk][mc + 2] = b.z; Bs[kk][mc + 3] = b.w;
        __syncthreads();
#pragma unroll
        for (int k = 0; k < 16; k++) {
            float ar[4], br[4];
#pragma unroll
            for (int i = 0; i < 4; i++) ar[i] = As[k][ty * 4 + i];
#pragma unroll
            for (int j = 0; j < 4; j++) br[j] = Bs[k][tx * 4 + j];
#pragma unroll
            for (int i = 0; i < 4; i++)
#pragma unroll
                for (int j = 0; j < 4; j++) acc[i][j] = fmaf(ar[i], br[j], acc[i][j]);
        }
    }
#pragma unroll
    for (int i = 0; i < 4; i++)
#pragma unroll
        for (int j = 0; j < 4; j++)
            C[(long)(bm + ty * 4 + i) * ldc + bn + tx * 4 + j] = alpha * acc[i][j];
}

// In-place row softmax over rows of length SEQ (=2048). One block per row.
__global__ __launch_bounds__(256) void softmax_rows(float* __restrict__ attn)
{
    const long row = blockIdx.x;
    float* p = attn + row * (long)SEQ;
    const int t = threadIdx.x;
    float4 v0 = *(const float4*)(p + t * 8);
    float4 v1 = *(const float4*)(p + t * 8 + 4);

    float m = fmaxf(fmaxf(fmaxf(v0.x, v0.y), fmaxf(v0.z, v0.w)),
                    fmaxf(fmaxf(v1.x, v1.y), fmaxf(v1.z, v1.w)));
#pragma unroll
    for (int off = 32; off > 0; off >>= 1) m = fmaxf(m, __shfl_xor(m, off));
    __shared__ float sm[4];
    __shared__ float ss[4];
    const int wave = t >> 6;
    if ((t & 63) == 0) sm[wave] = m;
    __syncthreads();
    m = fmaxf(fmaxf(sm[0], sm[1]), fmaxf(sm[2], sm[3]));

    v0.x = __expf(v0.x - m); v0.y = __expf(v0.y - m);
    v0.z = __expf(v0.z - m); v0.w = __expf(v0.w - m);
    v1.x = __expf(v1.x - m); v1.y = __expf(v1.y - m);
    v1.z = __expf(v1.z - m); v1.w = __expf(v1.w - m);

    float s = v0.x + v0.y + v0.z + v0.w + v1.x + v1.y + v1.z + v1.w;
#pragma unroll
    for (int off = 32; off > 0; off >>= 1) s += __shfl_xor(s, off);
    if ((t & 63) == 0) ss[wave] = s;
    __syncthreads();
    s = ss[0] + ss[1] + ss[2] + ss[3];
    const float inv = 1.0f / s;

    v0.x *= inv; v0.y *= inv; v0.z *= inv; v0.w *= inv;
    v1.x *= inv; v1.y *= inv; v1.z *= inv; v1.w *= inv;
    *(float4*)(p + t * 8)     = v0;
    *(float4*)(p + t * 8 + 4) = v1;
}

extern "C" void kernel_launch(void* const* d_in, const int* in_sizes, int n_in,
                              void* d_out, int out_size, void* d_ws, size_t ws_size,
                              hipStream_t stream)
{
    const float* q  = (const float*)d_in[0];
    const float* k  = (const float*)d_in[1];
    const float* v  = (const float*)d_in[2];
    const float* Wq = (const float*)d_in[3];
    const float* Wk = (const float*)d_in[4];
    const float* Wv = (const float*)d_in[5];

    float* out  = (float*)d_out;                                   // [8,2048,512]
    float* attn = (float*)d_out + (size_t)BATCH * SEQ * DIM;       // [8,2048,2048]

    float* T   = (float*)d_ws;                                     // [16384,512]
    float* vpT = T   + (size_t)BATCH * SEQ * DIM;                  // [8,512,2048]
    float* P   = vpT + (size_t)BATCH * SEQ * DIM;                  // [512,512]

    const float c = 0.044194173824159216f;  // 1/sqrt(512)

    // K1: P[d',d] = c^2 * sum_e Wk[e,d'] * Wq[e,d]   (fp32, exact-ish)
    gemm_tn_f32<<<dim3(8, 8), 256, 0, stream>>>(Wk, DIM, Wq, DIM, P, DIM, DIM, c * c);

    // K2 (split): T[n,d'] = sum_d q[n,d] * P[d',d]   -> [16384, 512]
    gemm_nt_mfma<3><<<dim3(4, 128, 1), 256, 0, stream>>>(
        q, DIM, 0, P, DIM, 0, T, DIM, 0, DIM, 1.0f);

    // K3 (split): dots[n,m] = c * sum_d' T[n,d'] * k[m,d']  per batch -> attn
    gemm_nt_mfma<3><<<dim3(16, 16, 8), 256, 0, stream>>>(
        T, DIM, (long)SEQ * DIM, k, DIM, (long)SEQ * DIM,
        attn, SEQ, (long)SEQ * SEQ, DIM, c);

    // K4: softmax in place
    softmax_rows<<<dim3(BATCH * SEQ), 256, 0, stream>>>(attn);

    // K5 (fp16): vpT[e,m] = c * sum_d Wv[e,d] * v[m,d]  per batch -> [512,2048]
    gemm_nt_mfma<1><<<dim3(16, 4, 8), 256, 0, stream>>>(
        Wv, DIM, 0, v, DIM, (long)SEQ * DIM,
        vpT, SEQ, (long)DIM * SEQ, DIM, c);

    // K6 (fp16): out[n,e] = sum_m attn[n,m] * vpT[e,m]  per batch
    gemm_nt_mfma<1><<<dim3(4, 16, 8), 256, 0, stream>>>(
        attn, SEQ, (long)SEQ * SEQ, vpT, SEQ, (long)DIM * SEQ,
        out, DIM, (long)SEQ * DIM, SEQ, 1.0f);
}

// Round 4
// 510.261 us; speedup vs baseline: 2.6423x; 1.1464x over previous
//
#include <hip/hip_runtime.h>
#include <math.h>

constexpr int BATCH = 8;
constexpr int SEQ   = 2048;
constexpr int DIM   = 512;

typedef _Float16 f16x8  __attribute__((ext_vector_type(8)));
typedef float    f32x16 __attribute__((ext_vector_type(16)));

__device__ __forceinline__ void gload_lds16(const void* g, void* l) {
    __builtin_amdgcn_global_load_lds(
        (const __attribute__((address_space(1))) void*)g,
        (__attribute__((address_space(3))) void*)l, 16, 0, 0);
}

// ---------------------------------------------------------------------------
// fp16 NT MFMA GEMM: C[m,n] = alpha * sum_k A[m,k]*B[n,k]; A,B row-major fp16.
// Block tile 128x256, BK=64. 4 waves in 2x2; wave tile 64x128 = 2x4 tiles of
// v_mfma_f32_32x32x16_f16. Staging via global_load_lds (16B/lane), K-loop is
// pure ds_read_b128 + MFMA (m97 structure).
// ---------------------------------------------------------------------------
template<bool OUT_F16>
__global__ __launch_bounds__(256, 2) void gemm_nt_f16(
    const _Float16* __restrict__ A, int lda, long sA,
    const _Float16* __restrict__ B, int ldb, long sB,
    void* __restrict__ Cv, int ldc, long sC,
    int K, float alpha)
{
    // LDS frag layout: [k-chunk][row][8 fp16] — 16B per (chunk,row), contiguous
    // in row so a wave's 64 lanes land at base + lane*16 (global_load_lds rule).
    __shared__ _Float16 As[8][128][8];   // 16 KB
    __shared__ _Float16 Bs[8][256][8];   // 32 KB

    const int bz = blockIdx.z;
    A += (long)bz * sA;  B += (long)bz * sB;
    const long bm = (long)blockIdx.y * 128;
    const long bn = (long)blockIdx.x * 256;
    const int t    = threadIdx.x;
    const int lane = t & 63;
    const int wave = t >> 6;
    const int wm = (wave >> 1) * 64;    // wave m-origin (2 tiles of 32)
    const int wn = (wave & 1) * 128;    // wave n-origin (4 tiles of 32)
    const int ml = lane & 31;
    const int kh = lane >> 5;           // k-half selector

    f32x16 acc[2][4] = {};

    for (int k0 = 0; k0 < K; k0 += 64) {
        // stage A: 8 chunks x 2 row-halves = 16 wave-segments, 4 per wave
#pragma unroll
        for (int s = 0; s < 4; s++) {
            const int idx = wave * 4 + s;
            const int ch  = idx >> 1;
            const int r0  = (idx & 1) * 64;
            const _Float16* gp = A + (bm + r0 + lane) * (long)lda + k0 + ch * 8;
            gload_lds16(gp, &As[ch][r0][0]);
        }
        // stage B: 8 chunks x 4 row-quarters = 32 wave-segments, 8 per wave
#pragma unroll
        for (int s = 0; s < 8; s++) {
            const int idx = wave * 8 + s;
            const int ch  = idx >> 2;
            const int r0  = (idx & 3) * 64;
            const _Float16* gp = B + (bn + r0 + lane) * (long)ldb + k0 + ch * 8;
            gload_lds16(gp, &Bs[ch][r0][0]);
        }
        __syncthreads();   // drains vmcnt -> LDS tiles valid

#pragma unroll
        for (int ks = 0; ks < 4; ks++) {
            const int ch = ks * 2 + kh;
            f16x8 a0 = *(const f16x8*)&As[ch][wm      + ml][0];
            f16x8 a1 = *(const f16x8*)&As[ch][wm + 32 + ml][0];
            f16x8 b0 = *(const f16x8*)&Bs[ch][wn       + ml][0];
            f16x8 b1 = *(const f16x8*)&Bs[ch][wn + 32  + ml][0];
            f16x8 b2 = *(const f16x8*)&Bs[ch][wn + 64  + ml][0];
            f16x8 b3 = *(const f16x8*)&Bs[ch][wn + 96  + ml][0];
            acc[0][0] = __builtin_amdgcn_mfma_f32_32x32x16_f16(a0, b0, acc[0][0], 0, 0, 0);
            acc[0][1] = __builtin_amdgcn_mfma_f32_32x32x16_f16(a0, b1, acc[0][1], 0, 0, 0);
            acc[0][2] = __builtin_amdgcn_mfma_f32_32x32x16_f16(a0, b2, acc[0][2], 0, 0, 0);
            acc[0][3] = __builtin_amdgcn_mfma_f32_32x32x16_f16(a0, b3, acc[0][3], 0, 0, 0);
            acc[1][0] = __builtin_amdgcn_mfma_f32_32x32x16_f16(a1, b0, acc[1][0], 0, 0, 0);
            acc[1][1] = __builtin_amdgcn_mfma_f32_32x32x16_f16(a1, b1, acc[1][1], 0, 0, 0);
            acc[1][2] = __builtin_amdgcn_mfma_f32_32x32x16_f16(a1, b2, acc[1][2], 0, 0, 0);
            acc[1][3] = __builtin_amdgcn_mfma_f32_32x32x16_f16(a1, b3, acc[1][3], 0, 0, 0);
        }
        __syncthreads();   // all LDS reads done before next iter's DMA
    }

    // Epilogue. C/D layout: col = lane&31; row = (rg&3) + 8*(rg>>2) + 4*(lane>>5)
    float*    Cf = (float*)Cv    + (OUT_F16 ? 0 : (long)bz * sC);
    _Float16* Ch = (_Float16*)Cv + (OUT_F16 ? (long)bz * sC : 0);
#pragma unroll
    for (int i = 0; i < 2; i++)
#pragma unroll
        for (int j = 0; j < 4; j++) {
            const long col = bn + wn + j * 32 + ml;
#pragma unroll
            for (int rg = 0; rg < 16; rg++) {
                const long row = bm + wm + i * 32 + (rg & 3) + 8 * (rg >> 2) + 4 * kh;
                if constexpr (OUT_F16)
                    Ch[row * (long)ldc + col] = (_Float16)(alpha * acc[i][j][rg]);
                else
                    Cf[row * (long)ldc + col] = alpha * acc[i][j][rg];
            }
        }
}

// ---------------------------------------------------------------------------
// Small fp32 TN GEMM: C[i,j] = alpha * sum_e A[e,i]*B[e,j] -> fp16 out.
// (P = c^2 Wk^T Wq). 512^3 only — accuracy anchor, fp32 vector math.
// ---------------------------------------------------------------------------
__global__ __launch_bounds__(256) void gemm_tn_f32(
    const float* __restrict__ A, int lda,
    const float* __restrict__ B, int ldb,
    _Float16* __restrict__ C, int ldc, int K, float alpha)
{
    __shared__ float As[16][68];
    __shared__ float Bs[16][68];
    const int bm = blockIdx.y * 64;
    const int bn = blockIdx.x * 64;
    const int t  = threadIdx.x;
    const int tx = t & 15, ty = t >> 4;
    const int kk = t >> 4, mc = (t & 15) * 4;

    float acc[4][4] = {};
    for (int k0 = 0; k0 < K; k0 += 16) {
        float4 a = *(const float4*)(A + (long)(k0 + kk) * lda + bm + mc);
        float4 b = *(const float4*)(B + (long)(k0 + kk) * ldb + bn + mc);
        __syncthreads();
        As[kk][mc] = a.x; As[kk][mc + 1] = a.y; As[kk][mc + 2] = a.z; As[kk][mc + 3] = a.w;
        Bs[kk][mc] = b.x; Bs[kk][mc + 1] = b.y; Bs[kk][mc + 2] = b.z; Bs[kk][mc + 3] = b.w;
        __syncthreads();
#pragma unroll
        for (int k = 0; k < 16; k++) {
            float ar[4], br[4];
#pragma unroll
            for (int i = 0; i < 4; i++) ar[i] = As[k][ty * 4 + i];
#pragma unroll
            for (int j = 0; j < 4; j++) br[j] = Bs[k][tx * 4 + j];
#pragma unroll
            for (int i = 0; i < 4; i++)
#pragma unroll
                for (int j = 0; j < 4; j++) acc[i][j] = fmaf(ar[i], br[j], acc[i][j]);
        }
    }
#pragma unroll
    for (int i = 0; i < 4; i++)
#pragma unroll
        for (int j = 0; j < 4; j++)
            C[(long)(bm + ty * 4 + i) * ldc + bn + tx * 4 + j] =
                (_Float16)(alpha * acc[i][j]);
}

// In-place row softmax (fp32) + fp16 copy for the PV GEMM. One block per row.
__global__ __launch_bounds__(256) void softmax_rows(
    float* __restrict__ attn, _Float16* __restrict__ attn16)
{
    const long row = blockIdx.x;
    float* p = attn + row * (long)SEQ;
    const int t = threadIdx.x;
    float4 v0 = *(const float4*)(p + t * 8);
    float4 v1 = *(const float4*)(p + t * 8 + 4);

    float m = fmaxf(fmaxf(fmaxf(v0.x, v0.y), fmaxf(v0.z, v0.w)),
                    fmaxf(fmaxf(v1.x, v1.y), fmaxf(v1.z, v1.w)));
#pragma unroll
    for (int off = 32; off > 0; off >>= 1) m = fmaxf(m, __shfl_xor(m, off));
    __shared__ float sm[4];
    __shared__ float ss[4];
    const int wave = t >> 6;
    if ((t & 63) == 0) sm[wave] = m;
    __syncthreads();
    m = fmaxf(fmaxf(sm[0], sm[1]), fmaxf(sm[2], sm[3]));

    v0.x = __expf(v0.x - m); v0.y = __expf(v0.y - m);
    v0.z = __expf(v0.z - m); v0.w = __expf(v0.w - m);
    v1.x = __expf(v1.x - m); v1.y = __expf(v1.y - m);
    v1.z = __expf(v1.z - m); v1.w = __expf(v1.w - m);

    float s = v0.x + v0.y + v0.z + v0.w + v1.x + v1.y + v1.z + v1.w;
#pragma unroll
    for (int off = 32; off > 0; off >>= 1) s += __shfl_xor(s, off);
    if ((t & 63) == 0) ss[wave] = s;
    __syncthreads();
    s = ss[0] + ss[1] + ss[2] + ss[3];
    const float inv = 1.0f / s;

    v0.x *= inv; v0.y *= inv; v0.z *= inv; v0.w *= inv;
    v1.x *= inv; v1.y *= inv; v1.z *= inv; v1.w *= inv;
    *(float4*)(p + t * 8)     = v0;
    *(float4*)(p + t * 8 + 4) = v1;

    f16x8 h;
    h[0] = (_Float16)v0.x; h[1] = (_Float16)v0.y;
    h[2] = (_Float16)v0.z; h[3] = (_Float16)v0.w;
    h[4] = (_Float16)v1.x; h[5] = (_Float16)v1.y;
    h[6] = (_Float16)v1.z; h[7] = (_Float16)v1.w;
    *(f16x8*)(attn16 + row * (long)SEQ + t * 8) = h;
}

// fp32 -> fp16 elementwise (8 per thread)
__global__ __launch_bounds__(256) void conv_f16(
    const float* __restrict__ in, _Float16* __restrict__ out, int n8)
{
    const int i = blockIdx.x * 256 + threadIdx.x;
    if (i >= n8) return;
    const float4 a = ((const float4*)in)[2 * i];
    const float4 b = ((const float4*)in)[2 * i + 1];
    f16x8 h;
    h[0] = (_Float16)a.x; h[1] = (_Float16)a.y; h[2] = (_Float16)a.z; h[3] = (_Float16)a.w;
    h[4] = (_Float16)b.x; h[5] = (_Float16)b.y; h[6] = (_Float16)b.z; h[7] = (_Float16)b.w;
    ((f16x8*)out)[i] = h;
}

extern "C" void kernel_launch(void* const* d_in, const int* in_sizes, int n_in,
                              void* d_out, int out_size, void* d_ws, size_t ws_size,
                              hipStream_t stream)
{
    const float* q  = (const float*)d_in[0];
    const float* k  = (const float*)d_in[1];
    const float* v  = (const float*)d_in[2];
    const float* Wq = (const float*)d_in[3];
    const float* Wk = (const float*)d_in[4];
    const float* Wv = (const float*)d_in[5];

    float* out  = (float*)d_out;                                 // [8,2048,512]
    float* attn = (float*)d_out + (size_t)BATCH * SEQ * DIM;     // [8,2048,2048]

    // Workspace layout (bytes). attn16 (67MB) overlays q16|k16|v16, all dead
    // by softmax time (K5 must run before softmax!).
    char* w = (char*)d_ws;
    _Float16* q16    = (_Float16*)(w);                           // 16.8 MB
    _Float16* k16    = (_Float16*)(w + 16777216);                // 16.8 MB
    _Float16* v16    = (_Float16*)(w + 33554432);                // 16.8 MB
    _Float16* attn16 = (_Float16*)(w);                           // 67 MB (overlay)
    _Float16* T16    = (_Float16*)(w + 67108864);                // 16.8 MB
    _Float16* vpT16  = (_Float16*)(w + 83886080);                // 16.8 MB
    _Float16* Wv16   = (_Float16*)(w + 100663296);               // 0.5 MB
    _Float16* P16    = (_Float16*)(w + 101187584);               // 0.5 MB

    const float c = 0.044194173824159216f;  // 1/sqrt(512)

    // Pre-convert fp32 -> fp16
    conv_f16<<<dim3(4096), 256, 0, stream>>>(q,  q16,  1048576);
    conv_f16<<<dim3(4096), 256, 0, stream>>>(k,  k16,  1048576);
    conv_f16<<<dim3(4096), 256, 0, stream>>>(v,  v16,  1048576);
    conv_f16<<<dim3(128),  256, 0, stream>>>(Wv, Wv16, 32768);

    // K1: P[d',d] = c^2 * sum_e Wk[e,d']*Wq[e,d]  (fp32 math, fp16 out)
    gemm_tn_f32<<<dim3(8, 8), 256, 0, stream>>>(Wk, DIM, Wq, DIM, P16, DIM, DIM, c * c);

    // K2: T[n,d'] = sum_d q[n,d]*P[d',d]  -> fp16 T  (M=16384, N=512, K=512)
    gemm_nt_f16<true><<<dim3(2, 128, 1), 256, 0, stream>>>(
        q16, DIM, 0, P16, DIM, 0, T16, DIM, 0, DIM, 1.0f);

    // K3: dots[n,m] = c * sum_d' T[n,d']*k[m,d']  per batch -> attn (fp32)
    gemm_nt_f16<false><<<dim3(8, 16, 8), 256, 0, stream>>>(
        T16, DIM, (long)SEQ * DIM, k16, DIM, (long)SEQ * DIM,
        attn, SEQ, (long)SEQ * SEQ, DIM, c);

    // K5: vpT[e,m] = c * sum_d Wv[e,d]*v[m,d]  per batch -> fp16 [512,2048]
    //     (before softmax: attn16 overlays v16)
    gemm_nt_f16<true><<<dim3(8, 4, 8), 256, 0, stream>>>(
        Wv16, DIM, 0, v16, DIM, (long)SEQ * DIM,
        vpT16, SEQ, (long)DIM * SEQ, DIM, c);

    // K4: softmax in place (fp32) + fp16 copy
    softmax_rows<<<dim3(BATCH * SEQ), 256, 0, stream>>>(attn, attn16);

    // K6: out[n,e] = sum_m attn[n,m]*vpT[e,m]  per batch -> fp32 out
    gemm_nt_f16<false><<<dim3(2, 16, 8), 256, 0, stream>>>(
        attn16, SEQ, (long)SEQ * SEQ, vpT16, SEQ, (long)DIM * SEQ,
        out, DIM, (long)SEQ * DIM, SEQ, 1.0f);
}